// Round 9
// baseline (220.173 us; speedup 1.0000x reference)
//
#include <hip/hip_runtime.h>
#include <hip/hip_bf16.h>
#include <stdint.h>

#define T_TOKENS 8192
#define D_DIM 1024
#define H_DIM 2048
#define N_EXPERTS 8

typedef __attribute__((ext_vector_type(8))) short bf16x8;
typedef __attribute__((ext_vector_type(4))) float f32x4;
typedef __attribute__((ext_vector_type(16))) float f32x16;

typedef __attribute__((address_space(1))) const void* gptr_t;
typedef __attribute__((address_space(3))) void* lptr_t;

__device__ __forceinline__ unsigned short f2bf(float f) {
  union { float f; unsigned int u; } x; x.f = f;
  unsigned int r = x.u + 0x7FFFu + ((x.u >> 16) & 1u);
  return (unsigned short)(r >> 16);
}
__device__ __forceinline__ float bf2f(unsigned short b) {
  union { unsigned int u; float f; } x; x.u = ((unsigned int)b) << 16;
  return x.f;
}

__device__ __forceinline__ void gload16(const void* g, void* l) {
  __builtin_amdgcn_global_load_lds((gptr_t)g, (lptr_t)l, 16, 0, 0);
}

// Sync discipline (rule #18: sched_barrier after inline-asm waits / raw barriers)
#define SBAR()   do { __builtin_amdgcn_s_barrier(); __builtin_amdgcn_sched_barrier(0); } while (0)
#define LGKM0()  do { asm volatile("s_waitcnt lgkmcnt(0)" ::: "memory"); __builtin_amdgcn_sched_barrier(0); } while (0)
#define LGKMN(n) do { asm volatile("s_waitcnt lgkmcnt(" #n ")" ::: "memory"); __builtin_amdgcn_sched_barrier(0); } while (0)
#define VMW(n)   do { __builtin_amdgcn_sched_barrier(0); asm volatile("s_waitcnt vmcnt(" #n ")" ::: "memory"); } while (0)

// ---------------------------------------------------------------------------
// fp32 -> bf16 conversion — round-1 structure (~36us total; 240MB roofline).
// ---------------------------------------------------------------------------
__global__ void cvt_f32_bf16_kernel(const float* __restrict__ in,
                                    unsigned short* __restrict__ out, int n) {
  int tid = blockIdx.x * blockDim.x + threadIdx.x;
  int stride = gridDim.x * blockDim.x;
  for (int i = tid * 4; i < n; i += stride * 4) {
    const float4 v = *reinterpret_cast<const float4*>(in + i);
    ushort4 o;
    o.x = f2bf(v.x); o.y = f2bf(v.y); o.z = f2bf(v.z); o.w = f2bf(v.w);
    *reinterpret_cast<ushort4*>(out + i) = o;
  }
}

// ---------------------------------------------------------------------------
// GEMM1: hsq[T,H] = bf16(relu(bf16(x @ w_up^T))^2).
// BM=256 BN=256 BK=64, 8 waves 2Mx4N, wave-tile 128x64, MFMA 32x32x16.
// R7/R8 spill fix: 32x32 shape -> 6 ds_read_b128 per kk-slice (4A+2B),
// peak 12 live fragments (48 VGPR) + acc 8xf32x16 (128) ~ 200 regs < 256.
// LDS ring-2 full K-tiles (lA 2x[256][64] + lB 2x[256][64] = 128KB, 1 blk/CU).
// Per tile: VMW(8), SBAR, 4 kk-slices {6 reads -> counted lgkmcnt -> 8 MFMA},
// SBAR, stage(t+2). Sync skeleton identical to R7/R8 (correctness-proven).
// Fragment layout 32x32x16: A row=lane&31, k=(lane>>5)*8+0..7 (contig 8);
// B col=lane&31 same k; C/D col=lane&31, row=(reg&3)+8*(reg>>2)+4*(lane>>5)
// (m74/m101). XOR swizzle: stage global granule (lane&7)^(lane>>3), read
// granule (kk*2+(lane>>5))^(lane&7); 2-way per 16-lane quarter = free.
// ---------------------------------------------------------------------------
__global__ __launch_bounds__(512, 2)
void gg1_256(const unsigned short* __restrict__ A,  // (T, D) bf16
             const unsigned short* __restrict__ B,  // (E, H, D) bf16
             const int* __restrict__ counts,
             unsigned short* __restrict__ O) {      // (T, H) bf16
  constexpr int K = D_DIM;
  constexpr int NT = K / 64;      // 16
  constexpr int AT = 256 * 64;    // shorts per tile buffer
  __shared__ short lA[2 * AT];    // 64 KB
  __shared__ short lB[2 * AT];    // 64 KB

  const int tid = threadIdx.x;
  const int wid = tid >> 6, lane = tid & 63;
  const int wr = wid >> 2, wc = wid & 3;          // 2M x 4N
  const int bid = blockIdx.x;
  const int cb = bid & 7, rb = bid >> 3;          // cb <-> XCD (grid 256)
  const int r0 = rb * 256, c0 = cb * 256;

  int csum[N_EXPERTS + 1];
  csum[0] = 0;
  for (int e = 0; e < N_EXPERTS; ++e) csum[e + 1] = csum[e] + counts[e];
  int eLo = 0;
  while (eLo < N_EXPERTS - 1 && csum[eLo + 1] <= r0) ++eLo;
  int eHi = eLo;
  while (eHi < N_EXPERTS - 1 && csum[eHi + 1] < r0 + 256) ++eHi;

  // staging (same as R7/R8): lane L -> row L>>3, LDS granule L&7; global
  // granule pre-swizzled (L&7)^(L>>3). Per wave: 4 A-lines + 4 B-lines.
  const int srow = lane >> 3;
  const int scol = ((lane & 7) ^ srow) * 8;
  const int aw = wid * 32;
  const int l31 = lane & 31, l7 = lane & 7;
  const int ls5 = lane >> 5;                      // 0..1 (k-half of 16)
  // read granule element-offsets per kk-slice (shorts):
  const int g0 = ((0 * 2 + ls5) ^ l7) * 8;
  const int g1 = ((1 * 2 + ls5) ^ l7) * 8;
  const int g2 = ((2 * 2 + ls5) ^ l7) * 8;
  const int g3 = ((3 * 2 + ls5) ^ l7) * 8;

  const unsigned short* Ab = A + (size_t)r0 * K;

  for (int e = eLo; e <= eHi; ++e) {
    const unsigned short* Bb = B + (size_t)e * H_DIM * K + (size_t)c0 * K;
    f32x16 acc[4][2];
#pragma unroll
    for (int mi = 0; mi < 4; ++mi)
#pragma unroll
      for (int ni = 0; ni < 2; ++ni)
#pragma unroll
        for (int q = 0; q < 16; ++q) acc[mi][ni][q] = 0.f;

#define SA1(T, J, BN) gload16(Ab + (size_t)(aw + (J) * 8 + srow) * K + (size_t)(T) * 64 + scol, \
                              &lA[(BN) * AT + (aw + (J) * 8) * 64])
#define SB1(T, J, BN) gload16(Bb + (size_t)(aw + (J) * 8 + srow) * K + (size_t)(T) * 64 + scol, \
                              &lB[(BN) * AT + (aw + (J) * 8) * 64])
#define STG(T, BN) do { SA1(T, 0, BN); SA1(T, 1, BN); SA1(T, 2, BN); SA1(T, 3, BN); \
                        SB1(T, 0, BN); SB1(T, 1, BN); SB1(T, 2, BN); SB1(T, 3, BN); } while (0)
// 6 reads for one kk-slice: 4 A-blocks (rows wr*128+mb*32+l31), 2 B-blocks
#define RD6(BI, G, FA, FB) do { \
    _Pragma("unroll") for (int m_ = 0; m_ < 4; ++m_) \
      FA[m_] = *(const bf16x8*)&lA[(BI) * AT + (wr * 128 + m_ * 32 + l31) * 64 + (G)]; \
    _Pragma("unroll") for (int n_ = 0; n_ < 2; ++n_) \
      FB[n_] = *(const bf16x8*)&lB[(BI) * AT + (wc * 64 + n_ * 32 + l31) * 64 + (G)]; \
  } while (0)
// 8 MFMA 32x32x16: 4 m-blocks x 2 n-blocks
#define MM8(FA, FB) do { \
    __builtin_amdgcn_s_setprio(1); \
    _Pragma("unroll") for (int m_ = 0; m_ < 4; ++m_) \
      _Pragma("unroll") for (int n_ = 0; n_ < 2; ++n_) \
        acc[m_][n_] = __builtin_amdgcn_mfma_f32_32x32x16_bf16(FA[m_], FB[n_], acc[m_][n_], 0, 0, 0); \
    __builtin_amdgcn_s_setprio(0); \
  } while (0)
// One K-tile: 4 kk-slices, 2-slice read pipeline (a0/b0 and a1/b1 alternate),
// counted in-order lgkmcnt isolates each slice's 6 reads.
#define KT1(T, BI, BN, WAIT, ST) do { \
    bf16x8 a0[4], b0[2], a1[4], b1[2]; \
    WAIT; SBAR(); \
    RD6(BI, g0, a0, b0); \
    RD6(BI, g1, a1, b1); \
    LGKMN(6); MM8(a0, b0); \
    RD6(BI, g2, a0, b0); \
    LGKMN(6); MM8(a1, b1); \
    RD6(BI, g3, a1, b1); \
    LGKMN(6); MM8(a0, b0); \
    LGKM0();  MM8(a1, b1); \
    SBAR(); \
    if (ST) STG((T) + 2, BN); \
  } while (0)

    STG(0, 0);
    STG(1, 1);

#pragma unroll 1
    for (int t = 0; t < NT - 2; ++t) {
      KT1(t, (t & 1), (t & 1), VMW(8), true);
    }
    KT1(NT - 2, ((NT - 2) & 1), 0, VMW(8), false);
    KT1(NT - 1, ((NT - 1) & 1), 0, VMW(0), false);

    // epilogue: 32x32 C/D layout col=lane&31, row=(reg&3)+8*(reg>>2)+4*(lane>>5)
    const int segLo = csum[e], segHi = csum[e + 1];
#pragma unroll
    for (int mi = 0; mi < 4; ++mi) {
      const int rowb = r0 + wr * 128 + mi * 32 + 4 * ls5;
#pragma unroll
      for (int ni = 0; ni < 2; ++ni) {
        const int col = c0 + wc * 64 + ni * 32 + l31;
#pragma unroll
        for (int q = 0; q < 16; ++q) {
          const int gr = rowb + (q & 3) + 8 * (q >> 2);
          if (gr >= segLo && gr < segHi) {
            float h = bf2f(f2bf(acc[mi][ni][q]));
            h = h > 0.f ? h : 0.f;
            O[(size_t)gr * H_DIM + col] = f2bf(h * h);
          }
        }
      }
    }
#undef SA1
#undef SB1
#undef STG
#undef RD6
#undef MM8
#undef KT1
  }
}

// ---------------------------------------------------------------------------
// GEMM2 — unchanged measured R5 kernel: BM=256 BN=128 BK=64, 8 waves 4Mx2N,
// 2 phases/K-tile, counted vmcnt(6), 4 K-half LDS slots, XOR swizzle.
// ---------------------------------------------------------------------------
template <int K, int N>
__global__ __launch_bounds__(512, 2)
void ggemm2(const unsigned short* __restrict__ A,
            const unsigned short* __restrict__ B,
            const int* __restrict__ counts,
            float* __restrict__ OF) {
  constexpr int NT = K / 64;
  constexpr int NCB = N / 128;
  __shared__ short lA[4 * 8192];
  __shared__ short lB[4 * 4096];

  const int tid = threadIdx.x;
  const int wid = tid >> 6, lane = tid & 63;
  const int wr = wid >> 1, wc = wid & 1;
  const int bid = blockIdx.x;
  const int cb = bid % NCB, rb = bid / NCB;
  const int r0 = rb * 256, c0 = cb * 128;

  int csum[N_EXPERTS + 1];
  csum[0] = 0;
  for (int e = 0; e < N_EXPERTS; ++e) csum[e + 1] = csum[e] + counts[e];
  int eLo = 0;
  while (eLo < N_EXPERTS - 1 && csum[eLo + 1] <= r0) ++eLo;
  int eHi = eLo;
  while (eHi < N_EXPERTS - 1 && csum[eHi + 1] < r0 + 256) ++eHi;

  const int srow = lane >> 2;
  const int scol = ((lane & 3) ^ ((lane >> 3) & 3)) * 8;
  const size_t aBase = (size_t)(r0 + wid * 16 + srow) * K + scol;
  const size_t bBase0 = (size_t)(c0 + wid * 16 + srow) * K + scol;
  const int ldsW = wid * 512;
  const int l15 = lane & 15;
  const int l4 = ((lane >> 4) ^ ((lane >> 1) & 3)) * 8;

  for (int e = eLo; e <= eHi; ++e) {
    const unsigned short* Be = B + (size_t)e * N * K;
    f32x4 acc[4][4];
#pragma unroll
    for (int mi = 0; mi < 4; ++mi)
#pragma unroll
      for (int ni = 0; ni < 4; ++ni) acc[mi][ni] = (f32x4){0.f, 0.f, 0.f, 0.f};

#define STAGE_A(t, h) do { const int s_ = (((t) & 1) << 1) | (h); \
    gload16(A + aBase + (size_t)(t) * 64 + (h) * 32,                 &lA[s_ * 8192 + ldsW]); \
    gload16(A + aBase + (size_t)128 * K + (size_t)(t) * 64 + (h) * 32, &lA[s_ * 8192 + ldsW + 4096]); } while (0)
#define STAGE_B(t, h) do { const int s_ = (((t) & 1) << 1) | (h); \
    gload16(Be + bBase0 + (size_t)(t) * 64 + (h) * 32, &lB[s_ * 4096 + ldsW]); } while (0)
#define G_RD(SLOT) do { \
    _Pragma("unroll") for (int m_ = 0; m_ < 4; ++m_) \
      fa[m_] = *(const bf16x8*)&lA[(SLOT) * 8192 + (wr * 64 + m_ * 16 + l15) * 32 + l4]; \
    _Pragma("unroll") for (int n_ = 0; n_ < 4; ++n_) \
      fb[n_] = *(const bf16x8*)&lB[(SLOT) * 4096 + (wc * 64 + n_ * 16 + l15) * 32 + l4]; \
  } while (0)
#define G_MM() do { \
    __builtin_amdgcn_s_setprio(1); \
    _Pragma("unroll") for (int m_ = 0; m_ < 4; ++m_) \
      _Pragma("unroll") for (int n_ = 0; n_ < 4; ++n_) \
        acc[m_][n_] = __builtin_amdgcn_mfma_f32_16x16x32_bf16(fa[m_], fb[n_], acc[m_][n_], 0, 0, 0); \
    __builtin_amdgcn_s_setprio(0); \
  } while (0)

    STAGE_A(0, 0); STAGE_B(0, 0); STAGE_A(0, 1); STAGE_B(0, 1);
    STAGE_A(1, 0); STAGE_B(1, 0);
    VMW(6); SBAR();

#pragma unroll 1
    for (int t = 0; t < NT - 2; ++t) {
      const int k0 = ((t & 1) << 1), k1 = k0 | 1;
      { bf16x8 fa[4], fb[4]; G_RD(k0); STAGE_A(t + 1, 1); STAGE_B(t + 1, 1); VMW(6); LGKM0(); G_MM(); SBAR(); }
      { bf16x8 fa[4], fb[4]; G_RD(k1); STAGE_A(t + 2, 0); STAGE_B(t + 2, 0); VMW(6); LGKM0(); G_MM(); SBAR(); }
    }
    {
      const int k0 = (((NT - 2) & 1) << 1), k1 = k0 | 1;
      { bf16x8 fa[4], fb[4]; G_RD(k0); STAGE_A(NT - 1, 1); STAGE_B(NT - 1, 1); VMW(6); LGKM0(); G_MM(); SBAR(); }
      { bf16x8 fa[4], fb[4]; G_RD(k1);                                        VMW(3); LGKM0(); G_MM(); SBAR(); }
    }
    {
      const int k0 = (((NT - 1) & 1) << 1), k1 = k0 | 1;
      { bf16x8 fa[4], fb[4]; G_RD(k0);                                        VMW(0); LGKM0(); G_MM(); SBAR(); }
      { bf16x8 fa[4], fb[4]; G_RD(k1);                                                LGKM0(); G_MM(); SBAR(); }
    }

    const int segLo = csum[e], segHi = csum[e + 1];
#pragma unroll
    for (int mi = 0; mi < 4; ++mi) {
      const int rowb = r0 + wr * 64 + mi * 16 + ((lane >> 4) << 2);
#pragma unroll
      for (int ni = 0; ni < 4; ++ni) {
        const int col = c0 + wc * 64 + ni * 16 + l15;
#pragma unroll
        for (int r = 0; r < 4; ++r) {
          const int gr = rowb + r;
          if (gr >= segLo && gr < segHi) {
            OF[(size_t)gr * N + col] = bf2f(f2bf(acc[mi][ni][r]));
          }
        }
      }
    }
#undef STAGE_A
#undef STAGE_B
#undef G_RD
#undef G_MM
  }
}

extern "C" void kernel_launch(void* const* d_in, const int* in_sizes, int n_in,
                              void* d_out, int out_size, void* d_ws, size_t ws_size,
                              hipStream_t stream) {
  const float* x = (const float*)d_in[0];
  const float* w_up = (const float*)d_in[1];
  const float* w_down = (const float*)d_in[2];
  const int* counts = (const int*)d_in[3];
  float* out = (float*)d_out;

  char* ws = (char*)d_ws;
  unsigned short* xb  = (unsigned short*)(ws);
  unsigned short* wub = (unsigned short*)(ws + (size_t)16 * 1024 * 1024);
  unsigned short* wdb = (unsigned short*)(ws + (size_t)48 * 1024 * 1024);
  unsigned short* hsq = (unsigned short*)(ws + (size_t)80 * 1024 * 1024);

  cvt_f32_bf16_kernel<<<2048, 256, 0, stream>>>(x, xb, T_TOKENS * D_DIM);
  cvt_f32_bf16_kernel<<<2048, 256, 0, stream>>>(w_up, wub, N_EXPERTS * H_DIM * D_DIM);
  cvt_f32_bf16_kernel<<<2048, 256, 0, stream>>>(w_down, wdb, N_EXPERTS * D_DIM * H_DIM);

  // GEMM1: 256x256 tile, 32x32x16 MFMA; grid 32 rb x 8 cb = 256 blocks
  gg1_256<<<256, 512, 0, stream>>>(xb, wub, counts, hsq);
  // GEMM2: R5 structure; grid 32 rb x 8 cb = 256 blocks
  ggemm2<H_DIM, D_DIM>
      <<<(T_TOKENS / 256) * (D_DIM / 128), 512, 0, stream>>>(hsq, wdb, counts, out);
}

// Round 10
// 167.871 us; speedup vs baseline: 1.3116x; 1.3116x over previous
//
#include <hip/hip_runtime.h>
#include <hip/hip_bf16.h>
#include <stdint.h>

#define T_TOKENS 8192
#define D_DIM 1024
#define H_DIM 2048
#define N_EXPERTS 8

typedef __attribute__((ext_vector_type(8))) short bf16x8;
typedef __attribute__((ext_vector_type(8))) unsigned short u16x8;
typedef __attribute__((ext_vector_type(4))) float f32x4;

typedef __attribute__((address_space(1))) const void* gptr_t;
typedef __attribute__((address_space(3))) void* lptr_t;

__device__ __forceinline__ unsigned short f2bf(float f) {
  union { float f; unsigned int u; } x; x.f = f;
  unsigned int r = x.u + 0x7FFFu + ((x.u >> 16) & 1u);
  return (unsigned short)(r >> 16);
}
__device__ __forceinline__ float bf2f(unsigned short b) {
  union { unsigned int u; float f; } x; x.u = ((unsigned int)b) << 16;
  return x.f;
}

__device__ __forceinline__ void gload16(const void* g, void* l) {
  __builtin_amdgcn_global_load_lds((gptr_t)g, (lptr_t)l, 16, 0, 0);
}

// Sync discipline (rule #18)
#define SBAR()  do { __builtin_amdgcn_s_barrier(); __builtin_amdgcn_sched_barrier(0); } while (0)
#define LGKM0() do { asm volatile("s_waitcnt lgkmcnt(0)" ::: "memory"); __builtin_amdgcn_sched_barrier(0); } while (0)
#define VMW(n)  do { __builtin_amdgcn_sched_barrier(0); asm volatile("s_waitcnt vmcnt(" #n ")" ::: "memory"); } while (0)

// ---------------------------------------------------------------------------
// fp32 -> bf16 conversion, single launch (R4's variant — best measured TOTAL
// config: graph-replay timing, not profiled-sum, is ground truth; rule #13).
//   blocks [0,4096) -> x; [4096,12288) -> w_up; [12288,20480) -> w_down.
// ---------------------------------------------------------------------------
__global__ void cvt_region(const float* __restrict__ x, const float* __restrict__ wu,
                           const float* __restrict__ wd,
                           unsigned short* __restrict__ xb, unsigned short* __restrict__ wub,
                           unsigned short* __restrict__ wdb) {
  const int b = blockIdx.x;
  const float* src; unsigned short* dst; int rb;
  if (b < 4096)        { src = x;  dst = xb;  rb = b; }
  else if (b < 12288)  { src = wu; dst = wub; rb = b - 4096; }
  else                 { src = wd; dst = wdb; rb = b - 12288; }
  const size_t off = ((size_t)rb * 256 + threadIdx.x) * 8;
  const float4 v0 = *reinterpret_cast<const float4*>(src + off);
  const float4 v1 = *reinterpret_cast<const float4*>(src + off + 4);
  u16x8 o;
  o[0] = f2bf(v0.x); o[1] = f2bf(v0.y); o[2] = f2bf(v0.z); o[3] = f2bf(v0.w);
  o[4] = f2bf(v1.x); o[5] = f2bf(v1.y); o[6] = f2bf(v1.z); o[7] = f2bf(v1.w);
  *reinterpret_cast<u16x8*>(dst + off) = o;
}

// ---------------------------------------------------------------------------
// Grouped GEMM — R5's proven 2-phase interior, re-parameterized for OCCUPANCY:
// BM=128 BN=128 BK=64, 4 waves 2Mx2N (wave-tile 64x64, acc[4][4]).
// LDS: 4 K-half slots x ([128][32] A + [128][32] B) = 32KB -> 3 blocks/CU
// (__launch_bounds__(256,3)). Rationale: every 1-block/CU design (R2-R9)
// pinned at ~660 TF because barriers stall the whole CU; m97/m114 show
// cross-block wave overlap is what absorbs the stage+barrier drain.
// Counted vmcnt: stage-op = 4 gloads (2A+2B per wave), 2 stage-ops in flight
// -> VMW(8) steady / VMW(4) / VMW(0) tail (mirror of R5's 6/3/0 accounting).
// XOR swizzle identical to R5 (measured 0 conflicts): stage global granule
// (lane&3)^((lane>>3)&3), LDS linear; read granule ((lane>>4)^((lane>>1)&3)).
// FUSE=true: O=bf16(relu(bf16(acc))^2) -> OB. FUSE=false: O=f32(bf16(acc)) -> OF.
// ---------------------------------------------------------------------------
template <int K, int N, bool FUSE>
__global__ __launch_bounds__(256, 3)
void ggemm(const unsigned short* __restrict__ A,
           const unsigned short* __restrict__ B,
           const int* __restrict__ counts,
           unsigned short* __restrict__ OB,
           float* __restrict__ OF) {
  constexpr int NT = K / 64;
  constexpr int NCB = N / 128;
  __shared__ short lA[4 * 4096];  // 4 slots x [128][32]
  __shared__ short lB[4 * 4096];

  const int tid = threadIdx.x;
  const int wid = tid >> 6, lane = tid & 63;
  const int wr = wid >> 1, wc = wid & 1;
  const int bid = blockIdx.x;
  const int cb = bid % NCB, rb = bid / NCB;  // NCB % 8 == 0 -> cb ~ XCD-stable
  const int r0 = rb * 128, c0 = cb * 128;

  int csum[N_EXPERTS + 1];
  csum[0] = 0;
  for (int e = 0; e < N_EXPERTS; ++e) csum[e + 1] = csum[e] + counts[e];
  int eLo = 0;
  while (eLo < N_EXPERTS - 1 && csum[eLo + 1] <= r0) ++eLo;
  int eHi = eLo;
  while (eHi < N_EXPERTS - 1 && csum[eHi + 1] < r0 + 128) ++eHi;

  // staging: lane -> row lane>>2 (16 rows/gload), XOR-pre-swizzled global granule
  const int srow = lane >> 2;
  const int scol = ((lane & 3) ^ ((lane >> 3) & 3)) * 8;
  const size_t aBase = (size_t)(r0 + wid * 16 + srow) * K + scol;
  const size_t bBase0 = (size_t)(c0 + wid * 16 + srow) * K + scol;
  const int ldsW = wid * 16 * 32;  // wave's 16-row chunk within a slot
  const int l15 = lane & 15;
  const int l4 = ((lane >> 4) ^ ((lane >> 1) & 3)) * 8;  // swizzled read granule

  for (int e = eLo; e <= eHi; ++e) {
    const unsigned short* Be = B + (size_t)e * N * K;
    f32x4 acc[4][4];
#pragma unroll
    for (int mi = 0; mi < 4; ++mi)
#pragma unroll
      for (int ni = 0; ni < 4; ++ni) acc[mi][ni] = (f32x4){0.f, 0.f, 0.f, 0.f};

// one stage-op = K-half h of tile t for BOTH operands: 4 gloads/wave
#define STAGE(t, h) do { const int s_ = (((t) & 1) << 1) | (h); \
    gload16(A + aBase + (size_t)(t) * 64 + (h) * 32,                &lA[s_ * 4096 + ldsW]); \
    gload16(A + aBase + (size_t)64 * K + (size_t)(t) * 64 + (h) * 32, &lA[s_ * 4096 + ldsW + 64 * 32]); \
    gload16(Be + bBase0 + (size_t)(t) * 64 + (h) * 32,                &lB[s_ * 4096 + ldsW]); \
    gload16(Be + bBase0 + (size_t)64 * K + (size_t)(t) * 64 + (h) * 32, &lB[s_ * 4096 + ldsW + 64 * 32]); \
  } while (0)
#define G_RD(SLOT) do { \
    _Pragma("unroll") for (int m_ = 0; m_ < 4; ++m_) \
      fa[m_] = *(const bf16x8*)&lA[(SLOT) * 4096 + (wr * 64 + m_ * 16 + l15) * 32 + l4]; \
    _Pragma("unroll") for (int n_ = 0; n_ < 4; ++n_) \
      fb[n_] = *(const bf16x8*)&lB[(SLOT) * 4096 + (wc * 64 + n_ * 16 + l15) * 32 + l4]; \
  } while (0)
#define G_MM() do { \
    __builtin_amdgcn_s_setprio(1); \
    _Pragma("unroll") for (int m_ = 0; m_ < 4; ++m_) \
      _Pragma("unroll") for (int n_ = 0; n_ < 4; ++n_) \
        acc[m_][n_] = __builtin_amdgcn_mfma_f32_16x16x32_bf16(fa[m_], fb[n_], acc[m_][n_], 0, 0, 0); \
    __builtin_amdgcn_s_setprio(0); \
  } while (0)

    // prologue: (0,h0),(0,h1),(1,h0) staged = 12 gloads; VMW(8) -> (0,h0) ready
    STAGE(0, 0); STAGE(0, 1); STAGE(1, 0);
    VMW(8); SBAR();

#pragma unroll 1
    for (int t = 0; t < NT - 2; ++t) {
      const int k0 = ((t & 1) << 1), k1 = k0 | 1;
      { bf16x8 fa[4], fb[4]; G_RD(k0); STAGE(t + 1, 1); VMW(8); LGKM0(); G_MM(); SBAR(); }
      { bf16x8 fa[4], fb[4]; G_RD(k1); STAGE(t + 2, 0); VMW(8); LGKM0(); G_MM(); SBAR(); }
    }
    {  // t = NT-2
      const int k0 = (((NT - 2) & 1) << 1), k1 = k0 | 1;
      { bf16x8 fa[4], fb[4]; G_RD(k0); STAGE(NT - 1, 1); VMW(8); LGKM0(); G_MM(); SBAR(); }
      { bf16x8 fa[4], fb[4]; G_RD(k1);                   VMW(4); LGKM0(); G_MM(); SBAR(); }
    }
    {  // t = NT-1
      const int k0 = (((NT - 1) & 1) << 1), k1 = k0 | 1;
      { bf16x8 fa[4], fb[4]; G_RD(k0);                   VMW(0); LGKM0(); G_MM(); SBAR(); }
      { bf16x8 fa[4], fb[4]; G_RD(k1);                           LGKM0(); G_MM(); SBAR(); }
    }

    // epilogue: C/D layout col=lane&15, row=(lane>>4)*4+reg (m89/m91)
    const int segLo = csum[e], segHi = csum[e + 1];
#pragma unroll
    for (int mi = 0; mi < 4; ++mi) {
      const int rowb = r0 + wr * 64 + mi * 16 + ((lane >> 4) << 2);
#pragma unroll
      for (int ni = 0; ni < 4; ++ni) {
        const int col = c0 + wc * 64 + ni * 16 + l15;
#pragma unroll
        for (int r = 0; r < 4; ++r) {
          const int gr = rowb + r;
          if (gr >= segLo && gr < segHi) {
            if (FUSE) {
              float h = bf2f(f2bf(acc[mi][ni][r]));
              h = h > 0.f ? h : 0.f;
              OB[(size_t)gr * N + col] = f2bf(h * h);
            } else {
              OF[(size_t)gr * N + col] = bf2f(f2bf(acc[mi][ni][r]));
            }
          }
        }
      }
    }
#undef STAGE
#undef G_RD
#undef G_MM
  }
}

extern "C" void kernel_launch(void* const* d_in, const int* in_sizes, int n_in,
                              void* d_out, int out_size, void* d_ws, size_t ws_size,
                              hipStream_t stream) {
  const float* x = (const float*)d_in[0];
  const float* w_up = (const float*)d_in[1];
  const float* w_down = (const float*)d_in[2];
  const int* counts = (const int*)d_in[3];
  float* out = (float*)d_out;

  char* ws = (char*)d_ws;
  unsigned short* xb  = (unsigned short*)(ws);
  unsigned short* wub = (unsigned short*)(ws + (size_t)16 * 1024 * 1024);
  unsigned short* wdb = (unsigned short*)(ws + (size_t)48 * 1024 * 1024);
  unsigned short* hsq = (unsigned short*)(ws + (size_t)80 * 1024 * 1024);

  cvt_region<<<20480, 256, 0, stream>>>(x, w_up, w_down, xb, wub, wdb);

  // GEMM1: hsq = bf16(relu(bf16(x @ w_up^T))^2); grid 64 rb x 16 cb = 1024
  ggemm<D_DIM, H_DIM, true>
      <<<(T_TOKENS / 128) * (H_DIM / 128), 256, 0, stream>>>(xb, wub, counts, hsq, nullptr);
  // GEMM2: out = f32(bf16(hsq @ w_down^T)); grid 64 rb x 8 cb = 512
  ggemm<H_DIM, D_DIM, false>
      <<<(T_TOKENS / 128) * (D_DIM / 128), 256, 0, stream>>>(hsq, wdb, counts, nullptr, out);
}

// Round 11
// 153.341 us; speedup vs baseline: 1.4358x; 1.0948x over previous
//
#include <hip/hip_runtime.h>
#include <hip/hip_bf16.h>
#include <stdint.h>

#define T_TOKENS 8192
#define D_DIM 1024
#define H_DIM 2048
#define N_EXPERTS 8

typedef __attribute__((ext_vector_type(8))) short bf16x8;
typedef __attribute__((ext_vector_type(8))) unsigned short u16x8;
typedef __attribute__((ext_vector_type(4))) float f32x4;

typedef __attribute__((address_space(1))) const void* gptr_t;
typedef __attribute__((address_space(3))) void* lptr_t;

__device__ __forceinline__ unsigned short f2bf(float f) {
  union { float f; unsigned int u; } x; x.f = f;
  unsigned int r = x.u + 0x7FFFu + ((x.u >> 16) & 1u);
  return (unsigned short)(r >> 16);
}
__device__ __forceinline__ float bf2f(unsigned short b) {
  union { unsigned int u; float f; } x; x.u = ((unsigned int)b) << 16;
  return x.f;
}

__device__ __forceinline__ void gload16(const void* g, void* l) {
  __builtin_amdgcn_global_load_lds((gptr_t)g, (lptr_t)l, 16, 0, 0);
}

// ---------------------------------------------------------------------------
// fp32 -> bf16 conversion, single launch (R4 variant — best measured TOTAL).
//   blocks [0,4096) -> x; [4096,12288) -> w_up; [12288,20480) -> w_down.
// ---------------------------------------------------------------------------
__global__ void cvt_region(const float* __restrict__ x, const float* __restrict__ wu,
                           const float* __restrict__ wd,
                           unsigned short* __restrict__ xb, unsigned short* __restrict__ wub,
                           unsigned short* __restrict__ wdb) {
  const int b = blockIdx.x;
  const float* src; unsigned short* dst; int rb;
  if (b < 4096)        { src = x;  dst = xb;  rb = b; }
  else if (b < 12288)  { src = wu; dst = wub; rb = b - 4096; }
  else                 { src = wd; dst = wdb; rb = b - 12288; }
  const size_t off = ((size_t)rb * 256 + threadIdx.x) * 8;
  const float4 v0 = *reinterpret_cast<const float4*>(src + off);
  const float4 v1 = *reinterpret_cast<const float4*>(src + off + 4);
  u16x8 o;
  o[0] = f2bf(v0.x); o[1] = f2bf(v0.y); o[2] = f2bf(v0.z); o[3] = f2bf(v0.w);
  o[4] = f2bf(v1.x); o[5] = f2bf(v1.y); o[6] = f2bf(v1.z); o[7] = f2bf(v1.w);
  *reinterpret_cast<u16x8*>(dst + off) = o;
}

// ---------------------------------------------------------------------------
// Grouped GEMM — R1's m97-structure kernel (PASSED at 65.6us with 12.6M bank
// conflicts) with ONE change: conflict-free XOR granule swizzle (rule #21).
//   - 128x128 tile, BK=64, 4 waves 2Mx2N (wave-tile 64x64, acc[4][4]).
//   - Single 32KB LDS buffer, plain __syncthreads, NO inline asm: the
//     compiler manages vmcnt/lgkmcnt, and cross-block wave overlap (3+
//     blocks/CU, m114) absorbs the barrier drain. Hand-scheduled variants
//     (R2-R10) all landed at 485-660 TF; m141: sched_barrier pinning hurts.
//   - Staging: lane L sources GLOBAL granule (L&7)^(L>>3) of row L>>3, LDS
//     dest linear -> LDS cell (row,g) holds global granule g^(row&7).
//     Coalescing preserved (each 8-lane group covers one full 128B row).
//   - Fragment read: logical granule kk*4+(lane>>4) at row r -> physical
//     (kk*4+(lane>>4))^(r&7), r&7 = lane&7. Per 16-lane quarter: 8 classes
//     x 2 lanes = 2-way = free (m136).
// FUSE=true: O=bf16(relu(bf16(acc))^2) -> OB. FUSE=false: O=f32(bf16(acc)).
// ---------------------------------------------------------------------------
template <int K, int N, bool FUSE>
__global__ void grouped_gemm_bt(const unsigned short* __restrict__ A,
                                const unsigned short* __restrict__ B,
                                const int* __restrict__ counts,
                                unsigned short* __restrict__ OB,
                                float* __restrict__ OF) {
  __shared__ short lA[128 * 64];
  __shared__ short lB[128 * 64];

  const int tid = threadIdx.x;
  const int wid = tid >> 6;
  const int lane = tid & 63;
  const int r0 = blockIdx.y * 128;
  const int c0 = blockIdx.x * 128;

  int csum[N_EXPERTS + 1];
  csum[0] = 0;
  for (int e = 0; e < N_EXPERTS; ++e) csum[e + 1] = csum[e] + counts[e];
  int eLo = 0;
  while (eLo < N_EXPERTS - 1 && csum[eLo + 1] <= r0) ++eLo;
  int eHi = eLo;
  while (eHi < N_EXPERTS - 1 && csum[eHi + 1] < r0 + 128) ++eHi;

  const int lrow = lane >> 3;                     // row within 8-row gload line
  const int lcolb = ((lane & 7) ^ lrow) * 8;      // pre-swizzled GLOBAL granule
  const int wr = wid >> 1, wc = wid & 1;
  const int l15 = lane & 15, l7 = lane & 7;
  // physical read granules (shorts) for kk=0,1: (kk*4+(lane>>4)) ^ (row&7)
  const int g0 = (((lane >> 4)) ^ l7) * 8;
  const int g1 = ((4 + (lane >> 4)) ^ l7) * 8;

  for (int e = eLo; e <= eHi; ++e) {
    const unsigned short* Be = B + (size_t)e * N * K;
    f32x4 acc[4][4];
#pragma unroll
    for (int mi = 0; mi < 4; ++mi)
#pragma unroll
      for (int ni = 0; ni < 4; ++ni)
        acc[mi][ni] = (f32x4){0.f, 0.f, 0.f, 0.f};

    for (int kt = 0; kt < K / 64; ++kt) {
      // Stage A tile [128][64] and B tile [128][64] into LDS (8 gloads/wave).
#pragma unroll
      for (int j = 0; j < 4; ++j) {
        const int rb = wid * 32 + j * 8;
        gload16(A + (size_t)(r0 + rb + lrow) * K + kt * 64 + lcolb, &lA[rb * 64]);
        gload16(Be + (size_t)(c0 + rb + lrow) * K + kt * 64 + lcolb, &lB[rb * 64]);
      }
      __syncthreads();  // compiler drains vmcnt before s_barrier
#pragma unroll
      for (int kk = 0; kk < 2; ++kk) {
        const int g = kk ? g1 : g0;
        bf16x8 af[4], bfr[4];
#pragma unroll
        for (int mi = 0; mi < 4; ++mi)
          af[mi] = *(const bf16x8*)&lA[(wr * 64 + mi * 16 + l15) * 64 + g];
#pragma unroll
        for (int ni = 0; ni < 4; ++ni)
          bfr[ni] = *(const bf16x8*)&lB[(wc * 64 + ni * 16 + l15) * 64 + g];
#pragma unroll
        for (int mi = 0; mi < 4; ++mi)
#pragma unroll
          for (int ni = 0; ni < 4; ++ni)
            acc[mi][ni] = __builtin_amdgcn_mfma_f32_16x16x32_bf16(af[mi], bfr[ni], acc[mi][ni], 0, 0, 0);
      }
      __syncthreads();
    }

    // Epilogue: C/D layout col=lane&15, row=(lane>>4)*4+reg (m89/m91 verified).
    const int segLo = csum[e], segHi = csum[e + 1];
#pragma unroll
    for (int mi = 0; mi < 4; ++mi) {
      const int rowb = r0 + wr * 64 + mi * 16 + ((lane >> 4) << 2);
#pragma unroll
      for (int ni = 0; ni < 4; ++ni) {
        const int col = c0 + wc * 64 + ni * 16 + l15;
#pragma unroll
        for (int r = 0; r < 4; ++r) {
          const int gr = rowb + r;
          if (gr >= segLo && gr < segHi) {
            float y = acc[mi][ni][r];
            if (FUSE) {
              float h = bf2f(f2bf(y));   // bf16 round (matches ref)
              h = h > 0.f ? h : 0.f;     // relu
              OB[(size_t)gr * N + col] = f2bf(h * h);  // bf16 square
            } else {
              OF[(size_t)gr * N + col] = bf2f(f2bf(y));  // bf16 round, fp32 store
            }
          }
        }
      }
    }
  }
}

extern "C" void kernel_launch(void* const* d_in, const int* in_sizes, int n_in,
                              void* d_out, int out_size, void* d_ws, size_t ws_size,
                              hipStream_t stream) {
  const float* x = (const float*)d_in[0];       // (T, D) fp32
  const float* w_up = (const float*)d_in[1];    // (E, H, D) fp32
  const float* w_down = (const float*)d_in[2];  // (E, D, H) fp32
  const int* counts = (const int*)d_in[3];      // (E,) int32
  float* out = (float*)d_out;                   // (T, D) fp32

  char* ws = (char*)d_ws;
  unsigned short* xb  = (unsigned short*)(ws);
  unsigned short* wub = (unsigned short*)(ws + (size_t)16 * 1024 * 1024);
  unsigned short* wdb = (unsigned short*)(ws + (size_t)48 * 1024 * 1024);
  unsigned short* hsq = (unsigned short*)(ws + (size_t)80 * 1024 * 1024);

  cvt_region<<<20480, 256, 0, stream>>>(x, w_up, w_down, xb, wub, wdb);

  // GEMM1: hsq = bf16(relu(bf16(x @ w_up^T))^2)  -> (T, H) bf16
  grouped_gemm_bt<D_DIM, H_DIM, true>
      <<<dim3(H_DIM / 128, T_TOKENS / 128), 256, 0, stream>>>(xb, wub, counts, hsq, nullptr);
  // GEMM2: out = float(bf16(hsq @ w_down^T)) -> (T, D) fp32
  grouped_gemm_bt<H_DIM, D_DIM, false>
      <<<dim3(D_DIM / 128, T_TOKENS / 128), 256, 0, stream>>>(hsq, wdb, counts, nullptr, out);
}